// Round 3
// baseline (1119.829 us; speedup 1.0000x reference)
//
#include <hip/hip_runtime.h>

#define NN    20000   // nodes
#define NRELH 16      // original relations
#define RTOT  33      // 2*16+1
#define NHID  64
#define NCLS  16

// ---- count (rel,dst)=cntA and (rel,src)=cntB over original edges ----
__global__ __launch_bounds__(256) void count_kernel(
    const int* __restrict__ src, const int* __restrict__ rel,
    const int* __restrict__ dst, int E,
    int* __restrict__ cntA, int* __restrict__ cntB) {
    int e = blockIdx.x * blockDim.x + threadIdx.x;
    if (e >= E) return;
    int r = rel[e];
    atomicAdd(&cntA[r * NN + dst[e]], 1);
    atomicAdd(&cntB[r * NN + src[e]], 1);
}

// ---- per-node augmented degree (out-deg + in-deg + 1 self), no atomics ----
__global__ __launch_bounds__(256) void deg_kernel(
    const int* __restrict__ cntA, const int* __restrict__ cntB,
    int* __restrict__ offsets) {
    int n = blockIdx.x * blockDim.x + threadIdx.x;
    if (n >= NN) return;
    int s = 1;
    for (int r = 0; r < NRELH; ++r) s += cntA[r * NN + n] + cntB[r * NN + n];
    offsets[n + 1] = s;
}

// ---- single-block exclusive scan of degrees; also drop self entries + init cursor ----
__global__ __launch_bounds__(256) void scan_kernel(
    int* __restrict__ offsets, int* __restrict__ cursor,
    unsigned* __restrict__ eidx) {
    __shared__ int part[256];
    int t = threadIdx.x;
    const int CH = (NN + 255) / 256;  // 79
    int base = t * CH, end = min(base + CH, NN);
    int s = 0;
    for (int n = base; n < end; ++n) s += offsets[n + 1];
    part[t] = s;
    __syncthreads();
    if (t == 0) {
        int run = 0;
        for (int i = 0; i < 256; ++i) { int v = part[i]; part[i] = run; run += v; }
        offsets[0] = 0;
    }
    __syncthreads();
    int run = part[t];
    for (int n = base; n < end; ++n) { run += offsets[n + 1]; offsets[n + 1] = run; }
    __syncthreads();
    for (int n = base; n < end; ++n) {
        int off = (n == 0) ? 0 : offsets[n];   // exclusive start of node n
        eidx[off] = (unsigned)n | (32u << 15) | (2u << 21);  // self-loop entry
        cursor[n] = off + 1;
    }
}

// ---- scatter original+inverse entries into CSR by owning node s ----
// entry packing: o[14:0] | r[20:15] | flag[22:21]  (flag 0=orig,1=inv,2=self)
__global__ __launch_bounds__(256) void scatter_kernel(
    const int* __restrict__ src, const int* __restrict__ rel,
    const int* __restrict__ dst, int E,
    int* __restrict__ cursor, unsigned* __restrict__ eidx) {
    int e = blockIdx.x * blockDim.x + threadIdx.x;
    if (e >= E) return;
    int r = rel[e], s0 = src[e], d = dst[e];
    int p1 = atomicAdd(&cursor[s0], 1);            // original: s=src, o=dst, r
    eidx[p1] = (unsigned)d | ((unsigned)r << 15);
    int p2 = atomicAdd(&cursor[d], 1);             // inverse: s=dst, o=src, r+16
    eidx[p2] = (unsigned)s0 | ((unsigned)(r + 16) << 15) | (1u << 21);
}

__device__ __forceinline__ float edge_val(unsigned e, int s, int* o, int* r,
                                          const int* __restrict__ cntA,
                                          const int* __restrict__ cntB) {
    *o = e & 0x7FFF;
    *r = (e >> 15) & 63;
    int flag = e >> 21;
    if (flag == 2) return 1.0f;
    if (flag == 1) return 1.0f / (float)cntA[(*r - 16) * NN + s];
    return 1.0f / (float)cntB[*r * NN + s];
}

// ---- layer 1: gather form, one wave per node, lane = hidden idx ----
__global__ __launch_bounds__(256) void layer1_gather(
    const unsigned* __restrict__ eidx, const int* __restrict__ offsets,
    const int* __restrict__ cntA, const int* __restrict__ cntB,
    const float* __restrict__ w1, const float* __restrict__ b1,
    float* __restrict__ h) {
    int wid  = (blockIdx.x * blockDim.x + threadIdx.x) >> 6;
    int lane = threadIdx.x & 63;
    if (wid >= NN) return;
    int s = wid;
    int k0 = offsets[s], k1 = offsets[s + 1];
    float acc = 0.0f;
    for (int k = k0; k < k1; ++k) {
        int o, r;
        float val = edge_val(eidx[k], s, &o, &r, cntA, cntB);
        acc += val * w1[(r * NN + o) * NHID + lane];  // 256B coalesced row
    }
    float v = acc + b1[lane];
    h[s * NHID + lane] = v > 0.0f ? v : 0.0f;
}

// ---- layer 2: per-node af tile in LDS (wave-private), then dense matvec ----
__global__ __launch_bounds__(256) void layer2_gather(
    const unsigned* __restrict__ eidx, const int* __restrict__ offsets,
    const int* __restrict__ cntA, const int* __restrict__ cntB,
    const float* __restrict__ h, const float* __restrict__ w2,
    const float* __restrict__ b2, float* __restrict__ out) {
    __shared__ float af[4 * RTOT * NHID];  // 33792 B, one 33x64 tile per wave
    int w = threadIdx.x >> 6, lane = threadIdx.x & 63;
    int s = blockIdx.x * 4 + w;
    if (s >= NN) return;
    float* myaf = &af[w * RTOT * NHID];
    for (int r = 0; r < RTOT; ++r) myaf[r * NHID + lane] = 0.0f;
    int k0 = offsets[s], k1 = offsets[s + 1];
    for (int k = k0; k < k1; ++k) {
        int o, r;
        float val = edge_val(eidx[k], s, &o, &r, cntA, cntB);
        float hv = h[o * NHID + lane];               // 256B coalesced row
        atomicAdd(&myaf[r * NHID + lane], val * hv); // ds_add_f32, lane-private
    }
    // out[s,c] = b2[c] + sum_r sum_i af[r][i] * w2[r,i,c]
    int c = lane & 15, part = lane >> 4;
    float acc = 0.0f;
    for (int r = 0; r < RTOT; ++r) {
        const float4* a4 = (const float4*)&myaf[r * NHID + part * 16];
        const float* wp = &w2[(r * NHID + part * 16) * NCLS + c];
#pragma unroll
        for (int q = 0; q < 4; ++q) {
            float4 a = a4[q];
            acc += a.x * wp[(q * 4 + 0) * NCLS] + a.y * wp[(q * 4 + 1) * NCLS]
                 + a.z * wp[(q * 4 + 2) * NCLS] + a.w * wp[(q * 4 + 3) * NCLS];
        }
    }
    acc += __shfl_xor(acc, 16, 64);
    acc += __shfl_xor(acc, 32, 64);
    if (lane < 16) out[s * NCLS + c] = acc + b2[c];
}

extern "C" void kernel_launch(void* const* d_in, const int* in_sizes, int n_in,
                              void* d_out, int out_size, void* d_ws, size_t ws_size,
                              hipStream_t stream) {
    const int*   src = (const int*)d_in[0];
    const int*   rel = (const int*)d_in[1];
    const int*   dst = (const int*)d_in[2];
    const float* w1  = (const float*)d_in[3];
    const float* b1  = (const float*)d_in[4];
    const float* w2  = (const float*)d_in[5];
    const float* b2  = (const float*)d_in[6];
    float* out = (float*)d_out;
    const int E  = in_sizes[0];
    const int EA = 2 * E + NN;

    // ws layout: cntA[16*NN] | cntB[16*NN] | offsets[NN+1] | cursor[NN] | eidx[EA] | h[NN*64]
    int*      cntA    = (int*)d_ws;
    int*      cntB    = cntA + NRELH * NN;
    int*      offsets = cntB + NRELH * NN;
    int*      cursor  = offsets + (NN + 1);
    unsigned* eidx    = (unsigned*)(cursor + NN);
    float*    h       = (float*)(eidx + EA);

    hipMemsetAsync(cntA, 0, (size_t)(2 * NRELH * NN) * 4, stream);

    count_kernel<<<(E + 255) / 256, 256, 0, stream>>>(src, rel, dst, E, cntA, cntB);
    deg_kernel<<<(NN + 255) / 256, 256, 0, stream>>>(cntA, cntB, offsets);
    scan_kernel<<<1, 256, 0, stream>>>(offsets, cursor, eidx);
    scatter_kernel<<<(E + 255) / 256, 256, 0, stream>>>(src, rel, dst, E, cursor, eidx);

    layer1_gather<<<(NN * 64) / 256, 256, 0, stream>>>(eidx, offsets, cntA, cntB, w1, b1, h);
    layer2_gather<<<(NN + 3) / 4, 256, 0, stream>>>(eidx, offsets, cntA, cntB, h, w2, b2, out);
}

// Round 4
// 520.898 us; speedup vs baseline: 2.1498x; 2.1498x over previous
//
#include <hip/hip_runtime.h>

#define NN    20000   // nodes
#define NRELH 16      // original relations
#define RTOT  33      // 2*16+1
#define NHID  64
#define NCLS  16
#define W2PAD 18      // padded words per (r,i) row of w2 in LDS (72B, conflict-free b64)

typedef unsigned int u32;

// ---- count (rel,dst)=cntA and (rel,src)=cntB over original edges ----
__global__ __launch_bounds__(256) void count_kernel(
    const int* __restrict__ src, const int* __restrict__ rel,
    const int* __restrict__ dst, int E,
    int* __restrict__ cntA, int* __restrict__ cntB) {
    int e = blockIdx.x * 256 + threadIdx.x;
    if (e >= E) return;
    int r = rel[e];
    atomicAdd(&cntA[r * NN + dst[e]], 1);
    atomicAdd(&cntB[r * NN + src[e]], 1);
}

// ---- per-node degree (orig+inv, no self), padded to multiple of 4 ----
__global__ __launch_bounds__(256) void deg_kernel(
    const int* __restrict__ cntA, const int* __restrict__ cntB,
    int* __restrict__ offsets) {
    int n = blockIdx.x * 256 + threadIdx.x;
    if (n >= NN) return;
    int d = 0;
    for (int r = 0; r < NRELH; ++r) d += cntA[r * NN + n] + cntB[r * NN + n];
    offsets[n + 1] = (d + 3) & ~3;
}

// ---- single-block in-place scan: offsets[n] = start of node n ----
__global__ __launch_bounds__(256) void scan_kernel(int* __restrict__ offsets) {
    __shared__ int part[256];
    int t = threadIdx.x;
    const int CH = (NN + 255) / 256;
    int base = t * CH, end = min(base + CH, NN);
    int s = 0;
    for (int n = base; n < end; ++n) s += offsets[n + 1];
    part[t] = s;
    __syncthreads();
    if (t == 0) {
        int run = 0;
        for (int i = 0; i < 256; ++i) { int v = part[i]; part[i] = run; run += v; }
        offsets[0] = 0;
    }
    __syncthreads();
    int run = part[t];
    for (int n = base; n < end; ++n) { run += offsets[n + 1]; offsets[n + 1] = run; }
}

// ---- per-(node,rel) cursors (relation-sorted layout) + pad-entry fill ----
__global__ __launch_bounds__(256) void cursor_pad_kernel(
    const int* __restrict__ cntA, const int* __restrict__ cntB,
    const int* __restrict__ offsets,
    int* __restrict__ curA, int* __restrict__ curB,
    u32* __restrict__ eidx, float* __restrict__ vals) {
    int n = blockIdx.x * 256 + threadIdx.x;
    if (n >= NN) return;
    int p = offsets[n];
    for (int r = 0; r < NRELH; ++r) { curB[r * NN + n] = p; p += cntB[r * NN + n]; }
    for (int r = 0; r < NRELH; ++r) { curA[r * NN + n] = p; p += cntA[r * NN + n]; }
    int pend = offsets[n + 1];
    // pad entries: o=0, r=32 (valid w1 row), val=0 -> harmless in both layers
    for (; p < pend; ++p) { eidx[p] = (32u << 15); vals[p] = 0.0f; }
}

// ---- scatter edges into relation-sorted CSR with precomputed vals ----
__global__ __launch_bounds__(256) void scatter_kernel(
    const int* __restrict__ src, const int* __restrict__ rel,
    const int* __restrict__ dst, int E,
    const int* __restrict__ cntA, const int* __restrict__ cntB,
    int* __restrict__ curA, int* __restrict__ curB,
    u32* __restrict__ eidx, float* __restrict__ vals) {
    int e = blockIdx.x * 256 + threadIdx.x;
    if (e >= E) return;
    int r = rel[e], s0 = src[e], d = dst[e];
    float vb = 1.0f / (float)cntB[r * NN + s0];         // orig, owned by s=src
    int p1 = atomicAdd(&curB[r * NN + s0], 1);
    eidx[p1] = (u32)d | ((u32)r << 15);
    vals[p1] = vb;
    float va = 1.0f / (float)cntA[r * NN + d];          // inverse, owned by s=dst
    int p2 = atomicAdd(&curA[r * NN + d], 1);
    eidx[p2] = (u32)s0 | ((u32)(r + 16) << 15);
    vals[p2] = va;
}

// ---- layer 1: one wave per node, lane = hidden idx, 4x unrolled gather ----
__global__ __launch_bounds__(256) void layer1_gather(
    const u32* __restrict__ eidx, const int* __restrict__ offsets,
    const float* __restrict__ vals,
    const float* __restrict__ w1, const float* __restrict__ b1,
    float* __restrict__ h) {
    int wid  = (blockIdx.x * 256 + threadIdx.x) >> 6;
    int lane = threadIdx.x & 63;
    if (wid >= NN) return;
    int s = wid;
    float acc = w1[(2 * NRELH * NN + s) * NHID + lane];  // self loop, val=1
    int k0 = offsets[s], k1 = offsets[s + 1];
    for (int k = k0; k < k1; k += 4) {
        uint4  e4 = *(const uint4*)&eidx[k];
        float4 v4 = *(const float4*)&vals[k];
        int row0 = (int)(e4.x >> 15) * NN + (int)(e4.x & 0x7FFF);
        int row1 = (int)(e4.y >> 15) * NN + (int)(e4.y & 0x7FFF);
        int row2 = (int)(e4.z >> 15) * NN + (int)(e4.z & 0x7FFF);
        int row3 = (int)(e4.w >> 15) * NN + (int)(e4.w & 0x7FFF);
        float g0 = w1[row0 * NHID + lane];
        float g1 = w1[row1 * NHID + lane];
        float g2 = w1[row2 * NHID + lane];
        float g3 = w1[row3 * NHID + lane];
        acc += v4.x * g0 + v4.y * g1 + v4.z * g2 + v4.w * g3;
    }
    float v = acc + b1[lane];
    h[s * NHID + lane] = v > 0.0f ? v : 0.0f;
}

// ---- layer 2: relation-sorted walk + register fold, w2 in LDS ----
__global__ __launch_bounds__(1024) void layer2_fold(
    const u32* __restrict__ eidx, const int* __restrict__ offsets,
    const float* __restrict__ vals,
    const float* __restrict__ h, const float* __restrict__ w2,
    const float* __restrict__ b2, float* __restrict__ out) {
    __shared__ float w2L[RTOT * NHID * W2PAD];  // 152064 B
    int tid = threadIdx.x;
    for (int idx = tid; idx < RTOT * NHID * NCLS; idx += 1024) {
        int c = idx & 15;
        int ri = idx >> 4;                       // r*64 + i
        w2L[ri * W2PAD + c] = w2[idx];           // coalesced read
    }
    __syncthreads();
    int w = tid >> 6, lane = tid & 63;
    for (int s = blockIdx.x * 16 + w; s < NN; s += gridDim.x * 16) {
        float acc16[16];
#pragma unroll
        for (int c = 0; c < 16; ++c) acc16[c] = 0.0f;
        auto FOLD = [&](int r, float a) {
            int b = (r * NHID + lane) * W2PAD;
#pragma unroll
            for (int q = 0; q < 8; ++q) {
                float2 wv = *(const float2*)&w2L[b + 2 * q];
                acc16[2 * q]     += a * wv.x;
                acc16[2 * q + 1] += a * wv.y;
            }
        };
        float hs = h[s * NHID + lane];
        FOLD(32, hs);                            // self loop, val=1
        int rcur = 32; float acc = 0.0f;
        int k0 = offsets[s], k1 = offsets[s + 1];
        for (int k = k0; k < k1; k += 4) {
            uint4  e4 = *(const uint4*)&eidx[k];
            float4 v4 = *(const float4*)&vals[k];
            int o0 = e4.x & 0x7FFF, r0 = e4.x >> 15;
            int o1 = e4.y & 0x7FFF, r1 = e4.y >> 15;
            int o2 = e4.z & 0x7FFF, r2 = e4.z >> 15;
            int o3 = e4.w & 0x7FFF, r3 = e4.w >> 15;
            float h0 = h[o0 * NHID + lane];
            float h1 = h[o1 * NHID + lane];
            float h2 = h[o2 * NHID + lane];
            float h3 = h[o3 * NHID + lane];
            if (r0 != rcur) { FOLD(rcur, acc); acc = 0.0f; rcur = r0; } acc += v4.x * h0;
            if (r1 != rcur) { FOLD(rcur, acc); acc = 0.0f; rcur = r1; } acc += v4.y * h1;
            if (r2 != rcur) { FOLD(rcur, acc); acc = 0.0f; rcur = r2; } acc += v4.z * h2;
            if (r3 != rcur) { FOLD(rcur, acc); acc = 0.0f; rcur = r3; } acc += v4.w * h3;
        }
        FOLD(rcur, acc);
        // cross-lane reduce: lane l (<16) ends with total for class c=l
        float s8[8];
#pragma unroll
        for (int j = 0; j < 8; ++j) {
            float p0 = __shfl_xor(acc16[2 * j], 1, 64);
            float p1 = __shfl_xor(acc16[2 * j + 1], 1, 64);
            float e0 = acc16[2 * j] + p0, e1 = acc16[2 * j + 1] + p1;
            s8[j] = (lane & 1) ? e1 : e0;
        }
        float s4[4];
#pragma unroll
        for (int j = 0; j < 4; ++j) {
            float p0 = __shfl_xor(s8[2 * j], 2, 64);
            float p1 = __shfl_xor(s8[2 * j + 1], 2, 64);
            float e0 = s8[2 * j] + p0, e1 = s8[2 * j + 1] + p1;
            s4[j] = (lane & 2) ? e1 : e0;
        }
        float s2[2];
#pragma unroll
        for (int j = 0; j < 2; ++j) {
            float p0 = __shfl_xor(s4[2 * j], 4, 64);
            float p1 = __shfl_xor(s4[2 * j + 1], 4, 64);
            float e0 = s4[2 * j] + p0, e1 = s4[2 * j + 1] + p1;
            s2[j] = (lane & 4) ? e1 : e0;
        }
        float p0 = __shfl_xor(s2[0], 8, 64);
        float p1 = __shfl_xor(s2[1], 8, 64);
        float e0 = s2[0] + p0, e1 = s2[1] + p1;
        float t = (lane & 8) ? e1 : e0;
        t += __shfl_xor(t, 16, 64);
        t += __shfl_xor(t, 32, 64);
        if (lane < 16) out[s * NCLS + lane] = t + b2[lane];
    }
}

extern "C" void kernel_launch(void* const* d_in, const int* in_sizes, int n_in,
                              void* d_out, int out_size, void* d_ws, size_t ws_size,
                              hipStream_t stream) {
    const int*   src = (const int*)d_in[0];
    const int*   rel = (const int*)d_in[1];
    const int*   dst = (const int*)d_in[2];
    const float* w1  = (const float*)d_in[3];
    const float* b1  = (const float*)d_in[4];
    const float* w2  = (const float*)d_in[5];
    const float* b2  = (const float*)d_in[6];
    float* out = (float*)d_out;
    const int E = in_sizes[0];
    const int ECAP = 2 * E + 4 * NN;

    // ws: cntA|cntB|curA|curB [16*NN each] | offsets[NN+4] | eidx[ECAP] | vals[ECAP] | h[NN*64]
    int*   cntA    = (int*)d_ws;
    int*   cntB    = cntA + NRELH * NN;
    int*   curA    = cntB + NRELH * NN;
    int*   curB    = curA + NRELH * NN;
    int*   offsets = curB + NRELH * NN;
    u32*   eidx    = (u32*)(offsets + NN + 4);
    float* vals    = (float*)(eidx + ECAP);
    float* h       = vals + ECAP;

    hipMemsetAsync(cntA, 0, (size_t)(2 * NRELH * NN) * 4, stream);

    count_kernel<<<(E + 255) / 256, 256, 0, stream>>>(src, rel, dst, E, cntA, cntB);
    deg_kernel<<<(NN + 255) / 256, 256, 0, stream>>>(cntA, cntB, offsets);
    scan_kernel<<<1, 256, 0, stream>>>(offsets);
    cursor_pad_kernel<<<(NN + 255) / 256, 256, 0, stream>>>(cntA, cntB, offsets,
                                                            curA, curB, eidx, vals);
    scatter_kernel<<<(E + 255) / 256, 256, 0, stream>>>(src, rel, dst, E, cntA, cntB,
                                                        curA, curB, eidx, vals);
    layer1_gather<<<(NN * 64) / 256, 256, 0, stream>>>(eidx, offsets, vals, w1, b1, h);
    layer2_fold<<<256, 1024, 0, stream>>>(eidx, offsets, vals, h, w2, b2, out);
}

// Round 5
// 460.492 us; speedup vs baseline: 2.4318x; 1.1312x over previous
//
#include <hip/hip_runtime.h>

#define NN    20000   // nodes
#define NRELH 16      // original relations
#define RTOT  33      // 2*16+1
#define NHID  64
#define NCLS  16
#define W2PAD 18      // padded words per (r,i) row of w2 in LDS

typedef unsigned int u32;

// ---- count (rel,dst)=cntA and (rel,src)=cntB over original edges ----
__global__ __launch_bounds__(256) void count_kernel(
    const int* __restrict__ src, const int* __restrict__ rel,
    const int* __restrict__ dst, int E,
    int* __restrict__ cntA, int* __restrict__ cntB) {
    int e = blockIdx.x * 256 + threadIdx.x;
    if (e >= E) return;
    int r = rel[e];
    atomicAdd(&cntA[r * NN + dst[e]], 1);
    atomicAdd(&cntB[r * NN + src[e]], 1);
}

// ---- merged: degree + segment allocation (unordered) + per-rel cursors + pad fill ----
__global__ __launch_bounds__(256) void alloc_kernel(
    const int* __restrict__ cntA, const int* __restrict__ cntB,
    int* __restrict__ gcount,
    int* __restrict__ curA, int* __restrict__ curB,
    int* __restrict__ nodeStart, int* __restrict__ nodeEnd,
    uint2* __restrict__ ent) {
    int n = blockIdx.x * 256 + threadIdx.x;
    if (n >= NN) return;
    int cb[NRELH], ca[NRELH];
    int d = 0;
#pragma unroll
    for (int r = 0; r < NRELH; ++r) { cb[r] = cntB[r * NN + n]; d += cb[r]; }
#pragma unroll
    for (int r = 0; r < NRELH; ++r) { ca[r] = cntA[r * NN + n]; d += ca[r]; }
    int pdeg = (d + 3) & ~3;
    int base = atomicAdd(gcount, pdeg);   // order across nodes irrelevant
    nodeStart[n] = base;
    nodeEnd[n]   = base + pdeg;
    int p = base;
#pragma unroll
    for (int r = 0; r < NRELH; ++r) { curB[r * NN + n] = p; p += cb[r]; }
#pragma unroll
    for (int r = 0; r < NRELH; ++r) { curA[r * NN + n] = p; p += ca[r]; }
    // pad entries: r=32 (valid w1 row), o=0, val=0 -> harmless in both layers
    for (; p < base + pdeg; ++p) ent[p] = make_uint2(32u << 15, 0u);
}

// ---- scatter edges into relation-sorted CSR, packed 8B entries ----
__global__ __launch_bounds__(256) void scatter_kernel(
    const int* __restrict__ src, const int* __restrict__ rel,
    const int* __restrict__ dst, int E,
    const int* __restrict__ cntA, const int* __restrict__ cntB,
    int* __restrict__ curA, int* __restrict__ curB,
    uint2* __restrict__ ent) {
    int e = blockIdx.x * 256 + threadIdx.x;
    if (e >= E) return;
    int r = rel[e], s0 = src[e], d = dst[e];
    float vb = 1.0f / (float)cntB[r * NN + s0];     // orig, owned by s=src
    int p1 = atomicAdd(&curB[r * NN + s0], 1);
    ent[p1] = make_uint2((u32)d | ((u32)r << 15), __float_as_uint(vb));
    float va = 1.0f / (float)cntA[r * NN + d];      // inverse, owned by s=dst
    int p2 = atomicAdd(&curA[r * NN + d], 1);
    ent[p2] = make_uint2((u32)s0 | ((u32)(r + 16) << 15), __float_as_uint(va));
}

// ---- layer 1: one wave per node, lane = hidden idx, 4x unrolled gather ----
__global__ __launch_bounds__(256) void layer1_gather(
    const uint2* __restrict__ ent,
    const int* __restrict__ nodeStart, const int* __restrict__ nodeEnd,
    const float* __restrict__ w1, const float* __restrict__ b1,
    float* __restrict__ h) {
    int wid  = (blockIdx.x * 256 + threadIdx.x) >> 6;
    int lane = threadIdx.x & 63;
    if (wid >= NN) return;
    int s = wid;
    int k0 = __builtin_amdgcn_readfirstlane(nodeStart[s]);
    int k1 = __builtin_amdgcn_readfirstlane(nodeEnd[s]);
    float acc = w1[(2 * NRELH * NN + s) * NHID + lane];  // self loop, val=1
    for (int k = k0; k < k1; k += 4) {
        uint4 ea = *(const uint4*)&ent[k];       // entries k, k+1
        uint4 eb = *(const uint4*)&ent[k + 2];   // entries k+2, k+3
        int row0 = (int)(ea.x >> 15) * NN + (int)(ea.x & 0x7FFF);
        int row1 = (int)(ea.z >> 15) * NN + (int)(ea.z & 0x7FFF);
        int row2 = (int)(eb.x >> 15) * NN + (int)(eb.x & 0x7FFF);
        int row3 = (int)(eb.z >> 15) * NN + (int)(eb.z & 0x7FFF);
        float g0 = w1[row0 * NHID + lane];
        float g1 = w1[row1 * NHID + lane];
        float g2 = w1[row2 * NHID + lane];
        float g3 = w1[row3 * NHID + lane];
        acc += __uint_as_float(ea.y) * g0 + __uint_as_float(ea.w) * g1
             + __uint_as_float(eb.y) * g2 + __uint_as_float(eb.w) * g3;
    }
    float v = acc + b1[lane];
    h[s * NHID + lane] = v > 0.0f ? v : 0.0f;
}

// ---- layer 2: relation-sorted walk + register fold, w2 in LDS ----
__global__ __launch_bounds__(1024) void layer2_fold(
    const uint2* __restrict__ ent,
    const int* __restrict__ nodeStart, const int* __restrict__ nodeEnd,
    const float* __restrict__ h, const float* __restrict__ w2,
    const float* __restrict__ b2, float* __restrict__ out) {
    __shared__ float w2L[RTOT * NHID * W2PAD];  // 152064 B
    int tid = threadIdx.x;
    for (int idx = tid; idx < RTOT * NHID * NCLS; idx += 1024) {
        int c = idx & 15;
        int ri = idx >> 4;                       // r*64 + i
        w2L[ri * W2PAD + c] = w2[idx];           // coalesced read
    }
    __syncthreads();
    int w = tid >> 6, lane = tid & 63;
    for (int s = blockIdx.x * 16 + w; s < NN; s += gridDim.x * 16) {
        float acc16[16];
#pragma unroll
        for (int c = 0; c < 16; ++c) acc16[c] = 0.0f;
        auto FOLD = [&](int r, float a) {
            int b = (r * NHID + lane) * W2PAD;
#pragma unroll
            for (int q = 0; q < 8; ++q) {
                float2 wv = *(const float2*)&w2L[b + 2 * q];
                acc16[2 * q]     += a * wv.x;
                acc16[2 * q + 1] += a * wv.y;
            }
        };
        float hs = h[s * NHID + lane];
        FOLD(32, hs);                            // self loop, val=1
        int rcur = 32; float acc = 0.0f;
        int k0 = __builtin_amdgcn_readfirstlane(nodeStart[s]);
        int k1 = __builtin_amdgcn_readfirstlane(nodeEnd[s]);
        for (int k = k0; k < k1; k += 4) {
            uint4 ea = *(const uint4*)&ent[k];
            uint4 eb = *(const uint4*)&ent[k + 2];
            int o0 = ea.x & 0x7FFF, r0 = ea.x >> 15;
            int o1 = ea.z & 0x7FFF, r1 = ea.z >> 15;
            int o2 = eb.x & 0x7FFF, r2 = eb.x >> 15;
            int o3 = eb.z & 0x7FFF, r3 = eb.z >> 15;
            float h0 = h[o0 * NHID + lane];
            float h1 = h[o1 * NHID + lane];
            float h2 = h[o2 * NHID + lane];
            float h3 = h[o3 * NHID + lane];
            if (r0 != rcur) { FOLD(rcur, acc); acc = 0.0f; rcur = r0; } acc += __uint_as_float(ea.y) * h0;
            if (r1 != rcur) { FOLD(rcur, acc); acc = 0.0f; rcur = r1; } acc += __uint_as_float(ea.w) * h1;
            if (r2 != rcur) { FOLD(rcur, acc); acc = 0.0f; rcur = r2; } acc += __uint_as_float(eb.y) * h2;
            if (r3 != rcur) { FOLD(rcur, acc); acc = 0.0f; rcur = r3; } acc += __uint_as_float(eb.w) * h3;
        }
        FOLD(rcur, acc);
        // cross-lane reduce: lane l (<16) ends with total for class c=l
        float s8[8];
#pragma unroll
        for (int j = 0; j < 8; ++j) {
            float p0 = __shfl_xor(acc16[2 * j], 1, 64);
            float p1 = __shfl_xor(acc16[2 * j + 1], 1, 64);
            float e0 = acc16[2 * j] + p0, e1 = acc16[2 * j + 1] + p1;
            s8[j] = (lane & 1) ? e1 : e0;
        }
        float s4[4];
#pragma unroll
        for (int j = 0; j < 4; ++j) {
            float p0 = __shfl_xor(s8[2 * j], 2, 64);
            float p1 = __shfl_xor(s8[2 * j + 1], 2, 64);
            float e0 = s8[2 * j] + p0, e1 = s8[2 * j + 1] + p1;
            s4[j] = (lane & 2) ? e1 : e0;
        }
        float s2[2];
#pragma unroll
        for (int j = 0; j < 2; ++j) {
            float p0 = __shfl_xor(s4[2 * j], 4, 64);
            float p1 = __shfl_xor(s4[2 * j + 1], 4, 64);
            float e0 = s4[2 * j] + p0, e1 = s4[2 * j + 1] + p1;
            s2[j] = (lane & 4) ? e1 : e0;
        }
        float p0 = __shfl_xor(s2[0], 8, 64);
        float p1 = __shfl_xor(s2[1], 8, 64);
        float e0 = s2[0] + p0, e1 = s2[1] + p1;
        float t = (lane & 8) ? e1 : e0;
        t += __shfl_xor(t, 16, 64);
        t += __shfl_xor(t, 32, 64);
        if (lane < 16) out[s * NCLS + lane] = t + b2[lane];
    }
}

extern "C" void kernel_launch(void* const* d_in, const int* in_sizes, int n_in,
                              void* d_out, int out_size, void* d_ws, size_t ws_size,
                              hipStream_t stream) {
    const int*   src = (const int*)d_in[0];
    const int*   rel = (const int*)d_in[1];
    const int*   dst = (const int*)d_in[2];
    const float* w1  = (const float*)d_in[3];
    const float* b1  = (const float*)d_in[4];
    const float* w2  = (const float*)d_in[5];
    const float* b2  = (const float*)d_in[6];
    float* out = (float*)d_out;
    const int E = in_sizes[0];
    const int ECAP = 2 * E + 4 * NN;

    // ws: cntA|cntB [16NN each] | gcount[4] | curA|curB [16NN] | nodeStart|nodeEnd [NN]
    //     | ent[ECAP] (uint2) | h[NN*64]
    int*   cntA      = (int*)d_ws;
    int*   cntB      = cntA + NRELH * NN;
    int*   gcount    = cntB + NRELH * NN;
    int*   curA      = gcount + 4;
    int*   curB      = curA + NRELH * NN;
    int*   nodeStart = curB + NRELH * NN;
    int*   nodeEnd   = nodeStart + NN;
    uint2* ent       = (uint2*)(nodeEnd + NN);
    float* h         = (float*)(ent + ECAP);

    // zero cntA, cntB, gcount in one memset
    hipMemsetAsync(cntA, 0, (size_t)(2 * NRELH * NN + 4) * 4, stream);

    count_kernel<<<(E + 255) / 256, 256, 0, stream>>>(src, rel, dst, E, cntA, cntB);
    alloc_kernel<<<(NN + 255) / 256, 256, 0, stream>>>(cntA, cntB, gcount, curA, curB,
                                                       nodeStart, nodeEnd, ent);
    scatter_kernel<<<(E + 255) / 256, 256, 0, stream>>>(src, rel, dst, E, cntA, cntB,
                                                        curA, curB, ent);
    layer1_gather<<<(NN * 64) / 256, 256, 0, stream>>>(ent, nodeStart, nodeEnd, w1, b1, h);
    layer2_fold<<<256, 1024, 0, stream>>>(ent, nodeStart, nodeEnd, h, w2, b2, out);
}